// Round 13
// baseline (253.001 us; speedup 1.0000x reference)
//
#include <hip/hip_runtime.h>
#include <hip/hip_bf16.h>
#include <stdint.h>

typedef short   s16x8  __attribute__((ext_vector_type(8)));
typedef float   f32x4a __attribute__((ext_vector_type(4)));
typedef int     i32x4v __attribute__((ext_vector_type(4)));
typedef unsigned short u16x4 __attribute__((ext_vector_type(4)));
typedef int     i32x4  __attribute__((ext_vector_type(4)));

#define D_IN   4096
#define D_OUT  4096
#define RANK   16
#define MROWS  8192   // 4 * 2048
#define NTI    32     // K-tiles of 128 bytes (i8): 4096/128

__device__ __forceinline__ uint16_t f32_to_bf16(float f) {
  union { float f; uint32_t u; } v; v.f = f;
  uint32_t u = v.u;
  return (uint16_t)((u + 0x7FFFu + ((u >> 16) & 1u)) >> 16);  // RNE
}

__device__ __forceinline__ void gload16(void* lds, const void* g) {
  __builtin_amdgcn_global_load_lds(
      (const __attribute__((address_space(1))) uint32_t*)g,
      (__attribute__((address_space(3))) uint32_t*)lds, 16, 0, 0);
}

// ---- 1) fused prep: [bid<2048] x-quant 4 rows | [else] qweight->i8 4 rows
// The two halves are independent streams sharing HBM BW; nontemporal
// writes keep x/qw L3-resident for the concurrent readers.
extern "C" __global__ __launch_bounds__(256) void k_prep(
    const float* __restrict__ x, const int* __restrict__ qw,
    const float* __restrict__ loraA, const float* __restrict__ loraB,
    signed char* __restrict__ xq, float* __restrict__ sx,
    signed char* __restrict__ wq, uint16_t* __restrict__ lb16,
    uint16_t* __restrict__ lab) {
  const int bid = blockIdx.x, tid = threadIdx.x;
  if (bid < 2048) {
    // ---- x-quant: 4 rows/block, 1 row/wave ----
    const int w = tid >> 6, l = tid & 63;
    const int64_t row = (int64_t)bid * 4 + w;
    const f32x4a* xr = (const f32x4a*)(x + row * D_IN);
    f32x4a v[16];
    float m = 0.f;
#pragma unroll
    for (int i = 0; i < 16; ++i) {
      v[i] = xr[i * 64 + l];
#pragma unroll
      for (int j = 0; j < 4; ++j) m = fmaxf(m, fabsf(v[i][j]));
    }
#pragma unroll
    for (int off = 32; off > 0; off >>= 1)
      m = fmaxf(m, __shfl_xor(m, off));
    m = fmaxf(m, 1e-20f);
    const float s = m / 127.f, rs = 127.f / m;
    int* qrow = (int*)(xq + row * D_IN);
#pragma unroll
    for (int i = 0; i < 16; ++i) {
      int b = 0;
#pragma unroll
      for (int j = 0; j < 4; ++j) {
        float t = fminf(fmaxf(rintf(v[i][j] * rs), -127.f), 127.f);
        b |= ((int)t & 255) << (8 * j);
      }
      __builtin_nontemporal_store(b, qrow + i * 64 + l);
    }
    if (l == 0) sx[row] = s;
  } else {
    // ---- weight conv: 4 rows/block (rows wb*4 .. wb*4+3) ----
    const int wb = bid - 2048;
#pragma unroll
    for (int r = 0; r < 4; ++r) {
      const int n = wb * 4 + r;
      const int* row = qw + (int64_t)n * D_IN + tid * 16;
      i32x4 o;
#pragma unroll
      for (int j = 0; j < 4; j++) {
        i32x4 u = *(const i32x4*)(row + j * 4);
        o[j] = (u[0] & 255) | ((u[1] & 255) << 8) | ((u[2] & 255) << 16)
             | (u[3] << 24);
      }
      __builtin_nontemporal_store(o,
          (i32x4*)(wq + (int64_t)n * D_IN + tid * 16));
      if (tid < RANK)
        lb16[n * RANK + tid] = f32_to_bf16(2.0f * loraB[n * RANK + tid]);
      if (n < RANK) {
        const float* ar = loraA + (int64_t)n * D_IN + tid * 16;
        uint16_t*    lr = lab   + (int64_t)n * D_IN + tid * 16;
        u16x4 q;
#pragma unroll
        for (int j = 0; j < 4; ++j) {
          f32x4a u = *(const f32x4a*)(ar + j * 4);
#pragma unroll
          for (int e = 0; e < 4; ++e) q[e] = f32_to_bf16(u[e]);
          *(u16x4*)(lr + j * 4) = q;
        }
      }
    }
  }
}

// ---- 2) xa[M][16] bf16 = sx[m] * (xq . lab^T)  (rank-16, MFMA) ---------
extern "C" __global__ __launch_bounds__(64) void k_xa(
    const signed char* __restrict__ xq, const float* __restrict__ sx,
    const uint16_t* __restrict__ lab, uint16_t* __restrict__ xa) {
  const int l = threadIdx.x;
  const int l15 = l & 15, lk = l >> 4;
  const int64_t row0 = (int64_t)blockIdx.x * 16;
  f32x4a acc = {0.f, 0.f, 0.f, 0.f};
  const signed char* xrow = xq + (row0 + l15) * D_IN + lk * 8;
  const uint16_t*    arow = lab + (int64_t)l15 * D_IN + lk * 8;
#pragma unroll 4
  for (int k0 = 0; k0 < D_IN; k0 += 32) {
    int64_t vv = *(const int64_t*)(xrow + k0);
    s16x8 bf = *(const s16x8*)(arow + k0);
    s16x8 af;
#pragma unroll
    for (int j = 0; j < 8; ++j) {
      signed char c = (signed char)(vv >> (8 * j));
      af[j] = (short)f32_to_bf16((float)c);       // exact (|c|<=127)
    }
    acc = __builtin_amdgcn_mfma_f32_16x16x32_bf16(af, bf, acc, 0, 0, 0);
  }
#pragma unroll
  for (int reg = 0; reg < 4; reg++) {
    int64_t mr = row0 + lk * 4 + reg;
    xa[mr * RANK + l15] = f32_to_bf16(acc[reg] * sx[mr]);
  }
}

// ---- 3) main GEMM (i8): unchanged from R12 (174 us) --------------------
extern "C" __global__ __launch_bounds__(512, 2) void k_gemm(
    const signed char* __restrict__ A, const signed char* __restrict__ B,
    const float* __restrict__ sx, const int* __restrict__ qscale,
    const float* __restrict__ meta, const float* __restrict__ bias,
    const uint16_t* __restrict__ xa, const uint16_t* __restrict__ lb16,
    float* __restrict__ out) {
  extern __shared__ char ldsc[];               // 131072 B
  char* aB = ldsc;                             // [2][32768]
  char* bB = ldsc + 65536;                     // [2][32768]

  const int tid = threadIdx.x;
  const int bid = blockIdx.x;                  // 512 blocks, 512%8==0
  const int xcd = bid & 7, loc = bid >> 3;
  const int mtile = xcd * 4 + (loc & 3);       // 0..31
  const int ntile = loc >> 2;                  // 0..15

  const int w = tid >> 6, l = tid & 63;
  const int wm = w >> 2, wn = w & 3;
  const int l15 = l & 15, lk = l >> 4;
  const int fro = lk * 256 + l15 * 16;         // frag byte offset in 1024-B run

  const signed char* Ag = A + (int64_t)mtile * 256 * D_IN;
  const signed char* Bg = B + (int64_t)ntile * 256 * D_IN;

  const int row_lo = ((tid >> 6) << 4) | (tid & 15);           // 0..127
  const int64_t s_lo = (int64_t)row_lo * D_IN + ((tid >> 4) & 3) * 16;
  const int64_t s_hi = s_lo + (int64_t)128 * D_IN;

#define STG_K0(bufp, gp, kb) {                                      \
    gload16((bufp) + (size_t)tid * 16,        (gp) + (kb) + s_lo);  \
    gload16((bufp) + (size_t)(512 + tid) * 16,(gp) + (kb) + s_hi); }
#define STG_K1(bufp, gp, kb) {                                           \
    gload16((bufp) + (size_t)(1024 + tid) * 16,(gp) + (kb) + 64 + s_lo); \
    gload16((bufp) + (size_t)(1536 + tid) * 16,(gp) + (kb) + 64 + s_hi); }

  i32x4v acc[8][4];
#pragma unroll
  for (int i = 0; i < 8; i++)
#pragma unroll
    for (int j = 0; j < 4; j++) acc[i][j] = (i32x4v){0, 0, 0, 0};

  STG_K0(aB, Ag, 0); STG_K0(bB, Bg, 0);
  STG_K1(aB, Ag, 0); STG_K1(bB, Bg, 0);
  asm volatile("s_waitcnt vmcnt(4)" ::: "memory");
  asm volatile("s_barrier" ::: "memory");

  i32x4v bf[4];

#define PHASE(MH, KC, STAGE_STMT, WAIT_STMT) {                               \
    i32x4v af[4];                                                            \
    _Pragma("unroll")                                                        \
    for (int mi = 0; mi < 4; ++mi)                                           \
      af[mi] = *(const i32x4v*)(cA + (KC) * 16384 +                          \
                                (wm * 8 + (MH) * 4 + mi) * 1024 + fro);      \
    if ((MH) == 0) {                                                         \
      _Pragma("unroll")                                                      \
      for (int ni = 0; ni < 4; ++ni)                                         \
        bf[ni] = *(const i32x4v*)(cB + (KC) * 16384 +                        \
                                  (wn * 4 + ni) * 1024 + fro);               \
    }                                                                        \
    STAGE_STMT;                                                              \
    asm volatile("s_barrier" ::: "memory");                                  \
    asm volatile("s_waitcnt lgkmcnt(0)" ::: "memory");                       \
    __builtin_amdgcn_s_setprio(1);                                           \
    _Pragma("unroll")                                                        \
    for (int mi = 0; mi < 4; ++mi)                                           \
      _Pragma("unroll")                                                      \
      for (int ni = 0; ni < 4; ++ni)                                         \
        acc[(MH) * 4 + mi][ni] = __builtin_amdgcn_mfma_i32_16x16x64_i8(      \
            af[mi], bf[ni], acc[(MH) * 4 + mi][ni], 0, 0, 0);                \
    __builtin_amdgcn_s_setprio(0);                                           \
    WAIT_STMT;                                                               \
    asm volatile("s_barrier" ::: "memory"); }

  for (int kt = 0; kt < NTI; ++kt) {
    const int cur = kt & 1;
    const char* cA = aB + cur * 32768;
    const char* cB = bB + cur * 32768;
    char* nA = aB + (cur ^ 1) * 32768;
    char* nB = bB + (cur ^ 1) * 32768;
    const int64_t kb = (int64_t)(kt + 1) * 128;
    const bool full = (kt < NTI - 1);

    PHASE(0, 0, if (full) STG_K0(nA, Ag, kb), )
    PHASE(1, 0, if (full) STG_K0(nB, Bg, kb),
          if (full) { asm volatile("s_waitcnt vmcnt(4)" ::: "memory"); }
          else      { asm volatile("s_waitcnt vmcnt(0)" ::: "memory"); })
    PHASE(0, 1, if (full) STG_K1(nA, Ag, kb), )
    PHASE(1, 1, if (full) STG_K1(nB, Bg, kb),
          if (full) { asm volatile("s_waitcnt vmcnt(4)" ::: "memory"); })
  }

  // ---- epilogue: dequant + bias + rank-16 LoRA (bf16 MFMA) -------------
  const float mv = meta[0];
  const int64_t mrow0 = (int64_t)mtile * 256 + wm * 128;
  const int ncol0 = ntile * 256 + wn * 64;

  s16x8 xf[8];
#pragma unroll
  for (int mi = 0; mi < 8; ++mi) {
    xf[mi] = (s16x8){0, 0, 0, 0, 0, 0, 0, 0};
    if (lk < 2)
      xf[mi] = *(const s16x8*)(xa + (mrow0 + mi * 16 + l15) * RANK + lk * 8);
  }
  s16x8 lbf[4];
#pragma unroll
  for (int ni = 0; ni < 4; ++ni) {
    lbf[ni] = (s16x8){0, 0, 0, 0, 0, 0, 0, 0};
    if (lk < 2)
      lbf[ni] = *(const s16x8*)(lb16 + (ncol0 + ni * 16 + l15) * RANK + lk * 8);
  }
  float sxv[8][4];
#pragma unroll
  for (int mi = 0; mi < 8; ++mi)
#pragma unroll
    for (int reg = 0; reg < 4; reg++)
      sxv[mi][reg] = sx[mrow0 + mi * 16 + lk * 4 + reg];

#pragma unroll
  for (int ni = 0; ni < 4; ++ni) {
    int n = ncol0 + ni * 16 + l15;
    float sr = (float)qscale[n] * mv;
    float bv = bias[n];
#pragma unroll
    for (int mi = 0; mi < 8; ++mi) {
      f32x4a lf = {0.f, 0.f, 0.f, 0.f};
      lf = __builtin_amdgcn_mfma_f32_16x16x32_bf16(xf[mi], lbf[ni], lf, 0, 0, 0);
      float* op = out + (mrow0 + mi * 16 + lk * 4) * (int64_t)D_OUT + n;
#pragma unroll
      for (int reg = 0; reg < 4; reg++)
        __builtin_nontemporal_store(
            (float)acc[mi][ni][reg] * (sxv[mi][reg] * sr) + lf[reg] + bv,
            op + (int64_t)reg * D_OUT);
    }
  }
#undef PHASE
#undef STG_K0
#undef STG_K1
}

extern "C" void kernel_launch(void* const* d_in, const int* in_sizes, int n_in,
                              void* d_out, int out_size, void* d_ws, size_t ws_size,
                              hipStream_t stream) {
  const float* x    = (const float*)d_in[0];
  const int*   qw   = (const int*)d_in[1];
  const int*   qs   = (const int*)d_in[2];
  const float* meta = (const float*)d_in[3];
  const float* bias = (const float*)d_in[4];
  const float* lA   = (const float*)d_in[5];
  const float* lB   = (const float*)d_in[6];
  float* out = (float*)d_out;

  // workspace layout (all 256-aligned)
  signed char* xq   = (signed char*)d_ws;                       // 33,554,432 B
  signed char* wq   = xq + (size_t)MROWS * D_IN;                // 16,777,216 B
  float*       sx   = (float*)(wq + (size_t)D_OUT * D_IN);      //     32,768 B
  uint16_t*    xa   = (uint16_t*)(sx + MROWS);                  //    262,144 B
  uint16_t*    lb16 = xa + (size_t)MROWS * RANK;                //    131,072 B
  uint16_t*    lab  = lb16 + (size_t)D_OUT * RANK;              //    131,072 B
  const size_t need = (size_t)MROWS * D_IN + (size_t)D_OUT * D_IN +
                      MROWS * 4 + (size_t)MROWS * RANK * 2 +
                      (size_t)D_OUT * RANK * 2 + (size_t)RANK * D_IN * 2;
  if (ws_size < need) return;

  const int lds_bytes = 131072;                                 // 128 KB
  (void)hipFuncSetAttribute((const void*)k_gemm,
                            hipFuncAttributeMaxDynamicSharedMemorySize,
                            lds_bytes);

  k_prep<<<2048 + D_OUT / 4, 256, 0, stream>>>(x, qw, lA, lB, xq, sx, wq,
                                               lb16, lab);
  k_xa<<<MROWS / 16, 64, 0, stream>>>(xq, sx, lab, xa);
  k_gemm<<<512, 512, lds_bytes, stream>>>(xq, wq, sx, qs, meta, bias,
                                          xa, lb16, out);
}

// Round 14
// 233.289 us; speedup vs baseline: 1.0845x; 1.0845x over previous
//
#include <hip/hip_runtime.h>
#include <hip/hip_bf16.h>
#include <stdint.h>

typedef short   s16x8  __attribute__((ext_vector_type(8)));
typedef float   f32x4a __attribute__((ext_vector_type(4)));
typedef int     i32x4v __attribute__((ext_vector_type(4)));
typedef unsigned short u16x4 __attribute__((ext_vector_type(4)));
typedef int     i32x4  __attribute__((ext_vector_type(4)));

#define D_IN   4096
#define D_OUT  4096
#define RANK   16
#define MROWS  8192   // 4 * 2048
#define NTI    32     // K-tiles of 128 bytes (i8): 4096/128

__device__ __forceinline__ uint16_t f32_to_bf16(float f) {
  union { float f; uint32_t u; } v; v.f = f;
  uint32_t u = v.u;
  return (uint16_t)((u + 0x7FFFu + ((u >> 16) & 1u)) >> 16);  // RNE
}

__device__ __forceinline__ void gload16(void* lds, const void* g) {
  __builtin_amdgcn_global_load_lds(
      (const __attribute__((address_space(1))) uint32_t*)g,
      (__attribute__((address_space(3))) uint32_t*)lds, 16, 0, 0);
}

// ---- 1) per-row symmetric i8 quant of x: xq[M][4096], sx[M] ------------
// REGULAR stores: xq must stay L3-resident for k_xa/k_gemm (R13 lesson:
// nontemporal here cost k_gemm +15 us).
extern "C" __global__ __launch_bounds__(256) void k_quant_x(
    const float* __restrict__ x, signed char* __restrict__ xq,
    float* __restrict__ sx) {
  const int w = threadIdx.x >> 6, l = threadIdx.x & 63;
  const int64_t row = (int64_t)blockIdx.x * 4 + w;
  const f32x4a* xr = (const f32x4a*)(x + row * D_IN);
  f32x4a v[16];
  float m = 0.f;
#pragma unroll
  for (int i = 0; i < 16; ++i) {
    v[i] = xr[i * 64 + l];
#pragma unroll
    for (int j = 0; j < 4; ++j) m = fmaxf(m, fabsf(v[i][j]));
  }
#pragma unroll
  for (int off = 32; off > 0; off >>= 1)
    m = fmaxf(m, __shfl_xor(m, off));
  m = fmaxf(m, 1e-20f);
  const float s = m / 127.f, rs = 127.f / m;
  int* qrow = (int*)(xq + row * D_IN);
#pragma unroll
  for (int i = 0; i < 16; ++i) {
    int b = 0;
#pragma unroll
    for (int j = 0; j < 4; ++j) {
      float t = fminf(fmaxf(rintf(v[i][j] * rs), -127.f), 127.f);
      b |= ((int)t & 255) << (8 * j);
    }
    qrow[i * 64 + l] = b;
  }
  if (l == 0) sx[row] = s;
}

// ---- 2) qweight int32 -> i8 wq; lb16 = bf16(2*loraB); lab = bf16(loraA)
extern "C" __global__ void k_conv_w(const int* __restrict__ qw,
                                    const float* __restrict__ loraA,
                                    const float* __restrict__ loraB,
                                    signed char* __restrict__ wq,
                                    uint16_t* __restrict__ lb16,
                                    uint16_t* __restrict__ lab) {
  const int n = blockIdx.x, t = threadIdx.x;
  const int* row = qw + (int64_t)n * D_IN + t * 16;
  i32x4 o;
#pragma unroll
  for (int j = 0; j < 4; j++) {
    i32x4 u = *(const i32x4*)(row + j * 4);
    o[j] = (u[0] & 255) | ((u[1] & 255) << 8) | ((u[2] & 255) << 16)
         | (u[3] << 24);
  }
  *(i32x4*)(wq + (int64_t)n * D_IN + t * 16) = o;
  if (t < RANK)
    lb16[n * RANK + t] = f32_to_bf16(2.0f * loraB[n * RANK + t]);
  if (n < RANK) {
    const float* ar = loraA + (int64_t)n * D_IN + t * 16;
    uint16_t*    lr = lab   + (int64_t)n * D_IN + t * 16;
    u16x4 q;
#pragma unroll
    for (int j = 0; j < 4; ++j) {
      f32x4a u = *(const f32x4a*)(ar + j * 4);
#pragma unroll
      for (int e = 0; e < 4; ++e) q[e] = f32_to_bf16(u[e]);
      *(u16x4*)(lr + j * 4) = q;
    }
  }
}

// ---- 3) xa[M][16] bf16 = sx[m] * (xq . lab^T)  (rank-16, MFMA) ---------
extern "C" __global__ __launch_bounds__(64) void k_xa(
    const signed char* __restrict__ xq, const float* __restrict__ sx,
    const uint16_t* __restrict__ lab, uint16_t* __restrict__ xa) {
  const int l = threadIdx.x;
  const int l15 = l & 15, lk = l >> 4;
  const int64_t row0 = (int64_t)blockIdx.x * 16;
  f32x4a acc = {0.f, 0.f, 0.f, 0.f};
  const signed char* xrow = xq + (row0 + l15) * D_IN + lk * 8;
  const uint16_t*    arow = lab + (int64_t)l15 * D_IN + lk * 8;
#pragma unroll 4
  for (int k0 = 0; k0 < D_IN; k0 += 32) {
    int64_t vv = *(const int64_t*)(xrow + k0);
    s16x8 bf = *(const s16x8*)(arow + k0);
    s16x8 af;
#pragma unroll
    for (int j = 0; j < 8; ++j) {
      signed char c = (signed char)(vv >> (8 * j));
      af[j] = (short)f32_to_bf16((float)c);       // exact (|c|<=127)
    }
    acc = __builtin_amdgcn_mfma_f32_16x16x32_bf16(af, bf, acc, 0, 0, 0);
  }
#pragma unroll
  for (int reg = 0; reg < 4; reg++) {
    int64_t mr = row0 + lk * 4 + reg;
    xa[mr * RANK + l15] = f32_to_bf16(acc[reg] * sx[mr]);
  }
}

// ---- 4) main GEMM (i8): 256x256 tile, BK=128 bytes, R4 schedule --------
// R12 exact (174 us, FETCH=compulsory, 0 conflicts, WRITE~=output).
extern "C" __global__ __launch_bounds__(512, 2) void k_gemm(
    const signed char* __restrict__ A, const signed char* __restrict__ B,
    const float* __restrict__ sx, const int* __restrict__ qscale,
    const float* __restrict__ meta, const float* __restrict__ bias,
    const uint16_t* __restrict__ xa, const uint16_t* __restrict__ lb16,
    float* __restrict__ out) {
  extern __shared__ char ldsc[];               // 131072 B
  char* aB = ldsc;                             // [2][32768]
  char* bB = ldsc + 65536;                     // [2][32768]

  const int tid = threadIdx.x;
  const int bid = blockIdx.x;                  // 512 blocks, 512%8==0
  const int xcd = bid & 7, loc = bid >> 3;
  const int mtile = xcd * 4 + (loc & 3);       // 0..31
  const int ntile = loc >> 2;                  // 0..15

  const int w = tid >> 6, l = tid & 63;
  const int wm = w >> 2, wn = w & 3;
  const int l15 = l & 15, lk = l >> 4;
  const int fro = lk * 256 + l15 * 16;         // frag byte offset in 1024-B run

  const signed char* Ag = A + (int64_t)mtile * 256 * D_IN;
  const signed char* Bg = B + (int64_t)ntile * 256 * D_IN;

  const int row_lo = ((tid >> 6) << 4) | (tid & 15);           // 0..127
  const int64_t s_lo = (int64_t)row_lo * D_IN + ((tid >> 4) & 3) * 16;
  const int64_t s_hi = s_lo + (int64_t)128 * D_IN;

#define STG_K0(bufp, gp, kb) {                                      \
    gload16((bufp) + (size_t)tid * 16,        (gp) + (kb) + s_lo);  \
    gload16((bufp) + (size_t)(512 + tid) * 16,(gp) + (kb) + s_hi); }
#define STG_K1(bufp, gp, kb) {                                           \
    gload16((bufp) + (size_t)(1024 + tid) * 16,(gp) + (kb) + 64 + s_lo); \
    gload16((bufp) + (size_t)(1536 + tid) * 16,(gp) + (kb) + 64 + s_hi); }

  i32x4v acc[8][4];
#pragma unroll
  for (int i = 0; i < 8; i++)
#pragma unroll
    for (int j = 0; j < 4; j++) acc[i][j] = (i32x4v){0, 0, 0, 0};

  STG_K0(aB, Ag, 0); STG_K0(bB, Bg, 0);
  STG_K1(aB, Ag, 0); STG_K1(bB, Bg, 0);
  asm volatile("s_waitcnt vmcnt(4)" ::: "memory");
  asm volatile("s_barrier" ::: "memory");

  i32x4v bf[4];

#define PHASE(MH, KC, STAGE_STMT, WAIT_STMT) {                               \
    i32x4v af[4];                                                            \
    _Pragma("unroll")                                                        \
    for (int mi = 0; mi < 4; ++mi)                                           \
      af[mi] = *(const i32x4v*)(cA + (KC) * 16384 +                          \
                                (wm * 8 + (MH) * 4 + mi) * 1024 + fro);      \
    if ((MH) == 0) {                                                         \
      _Pragma("unroll")                                                      \
      for (int ni = 0; ni < 4; ++ni)                                         \
        bf[ni] = *(const i32x4v*)(cB + (KC) * 16384 +                        \
                                  (wn * 4 + ni) * 1024 + fro);               \
    }                                                                        \
    STAGE_STMT;                                                              \
    asm volatile("s_barrier" ::: "memory");                                  \
    asm volatile("s_waitcnt lgkmcnt(0)" ::: "memory");                       \
    __builtin_amdgcn_s_setprio(1);                                           \
    _Pragma("unroll")                                                        \
    for (int mi = 0; mi < 4; ++mi)                                           \
      _Pragma("unroll")                                                      \
      for (int ni = 0; ni < 4; ++ni)                                         \
        acc[(MH) * 4 + mi][ni] = __builtin_amdgcn_mfma_i32_16x16x64_i8(      \
            af[mi], bf[ni], acc[(MH) * 4 + mi][ni], 0, 0, 0);                \
    __builtin_amdgcn_s_setprio(0);                                           \
    WAIT_STMT;                                                               \
    asm volatile("s_barrier" ::: "memory"); }

  for (int kt = 0; kt < NTI; ++kt) {
    const int cur = kt & 1;
    const char* cA = aB + cur * 32768;
    const char* cB = bB + cur * 32768;
    char* nA = aB + (cur ^ 1) * 32768;
    char* nB = bB + (cur ^ 1) * 32768;
    const int64_t kb = (int64_t)(kt + 1) * 128;
    const bool full = (kt < NTI - 1);

    PHASE(0, 0, if (full) STG_K0(nA, Ag, kb), )
    PHASE(1, 0, if (full) STG_K0(nB, Bg, kb),
          if (full) { asm volatile("s_waitcnt vmcnt(4)" ::: "memory"); }
          else      { asm volatile("s_waitcnt vmcnt(0)" ::: "memory"); })
    PHASE(0, 1, if (full) STG_K1(nA, Ag, kb), )
    PHASE(1, 1, if (full) STG_K1(nB, Bg, kb),
          if (full) { asm volatile("s_waitcnt vmcnt(4)" ::: "memory"); })
  }

  // ---- epilogue: dequant + bias + rank-16 LoRA (bf16 MFMA) -------------
  const float mv = meta[0];
  const int64_t mrow0 = (int64_t)mtile * 256 + wm * 128;
  const int ncol0 = ntile * 256 + wn * 64;

  s16x8 xf[8];
#pragma unroll
  for (int mi = 0; mi < 8; ++mi) {
    xf[mi] = (s16x8){0, 0, 0, 0, 0, 0, 0, 0};
    if (lk < 2)
      xf[mi] = *(const s16x8*)(xa + (mrow0 + mi * 16 + l15) * RANK + lk * 8);
  }
  s16x8 lbf[4];
#pragma unroll
  for (int ni = 0; ni < 4; ++ni) {
    lbf[ni] = (s16x8){0, 0, 0, 0, 0, 0, 0, 0};
    if (lk < 2)
      lbf[ni] = *(const s16x8*)(lb16 + (ncol0 + ni * 16 + l15) * RANK + lk * 8);
  }
  float sxv[8][4];
#pragma unroll
  for (int mi = 0; mi < 8; ++mi)
#pragma unroll
    for (int reg = 0; reg < 4; reg++)
      sxv[mi][reg] = sx[mrow0 + mi * 16 + lk * 4 + reg];

#pragma unroll
  for (int ni = 0; ni < 4; ++ni) {
    int n = ncol0 + ni * 16 + l15;
    float sr = (float)qscale[n] * mv;
    float bv = bias[n];
#pragma unroll
    for (int mi = 0; mi < 8; ++mi) {
      f32x4a lf = {0.f, 0.f, 0.f, 0.f};
      lf = __builtin_amdgcn_mfma_f32_16x16x32_bf16(xf[mi], lbf[ni], lf, 0, 0, 0);
      float* op = out + (mrow0 + mi * 16 + lk * 4) * (int64_t)D_OUT + n;
#pragma unroll
      for (int reg = 0; reg < 4; reg++)
        __builtin_nontemporal_store(
            (float)acc[mi][ni][reg] * (sxv[mi][reg] * sr) + lf[reg] + bv,
            op + (int64_t)reg * D_OUT);
    }
  }
#undef PHASE
#undef STG_K0
#undef STG_K1
}

extern "C" void kernel_launch(void* const* d_in, const int* in_sizes, int n_in,
                              void* d_out, int out_size, void* d_ws, size_t ws_size,
                              hipStream_t stream) {
  const float* x    = (const float*)d_in[0];
  const int*   qw   = (const int*)d_in[1];
  const int*   qs   = (const int*)d_in[2];
  const float* meta = (const float*)d_in[3];
  const float* bias = (const float*)d_in[4];
  const float* lA   = (const float*)d_in[5];
  const float* lB   = (const float*)d_in[6];
  float* out = (float*)d_out;

  // workspace layout (all 256-aligned)
  signed char* xq   = (signed char*)d_ws;                       // 33,554,432 B
  signed char* wq   = xq + (size_t)MROWS * D_IN;                // 16,777,216 B
  float*       sx   = (float*)(wq + (size_t)D_OUT * D_IN);      //     32,768 B
  uint16_t*    xa   = (uint16_t*)(sx + MROWS);                  //    262,144 B
  uint16_t*    lb16 = xa + (size_t)MROWS * RANK;                //    131,072 B
  uint16_t*    lab  = lb16 + (size_t)D_OUT * RANK;              //    131,072 B
  const size_t need = (size_t)MROWS * D_IN + (size_t)D_OUT * D_IN +
                      MROWS * 4 + (size_t)MROWS * RANK * 2 +
                      (size_t)D_OUT * RANK * 2 + (size_t)RANK * D_IN * 2;
  if (ws_size < need) return;

  const int lds_bytes = 131072;                                 // 128 KB
  (void)hipFuncSetAttribute((const void*)k_gemm,
                            hipFuncAttributeMaxDynamicSharedMemorySize,
                            lds_bytes);

  k_quant_x<<<MROWS / 4, 256, 0, stream>>>(x, xq, sx);
  k_conv_w<<<D_OUT, 256, 0, stream>>>(qw, lA, lB, wq, lb16, lab);
  k_xa<<<MROWS / 16, 64, 0, stream>>>(xq, sx, lab, xa);
  k_gemm<<<512, 512, lds_bytes, stream>>>(xq, wq, sx, qs, meta, bias,
                                          xa, lb16, out);
}